// Round 4
// baseline (721.079 us; speedup 1.0000x reference)
//
#include <hip/hip_runtime.h>

#define LQ 256
#define EDGES 65536
#define NNODE 1024
#define NT 512
#define EB 128

typedef __attribute__((ext_vector_type(8))) short bf16x8;
typedef __attribute__((ext_vector_type(4))) float f32x4;
typedef unsigned short ushort_t;
typedef unsigned int uint32;

constexpr float PW0c = 0.15811388300841897f;   // sqrt(1/40)
constexpr float PW1c = 0.25f;
constexpr float S3c  = 0.57735026918962576f;   // 1/sqrt(3)
constexpr float Kc   = 0.54772255750516611f;   // sqrt(3/10)

__device__ __forceinline__ ushort_t f2bf(float x){
  unsigned u = __float_as_uint(x);
  unsigned r = u + 0x7FFFu + ((u >> 16) & 1u);
  return (ushort_t)(r >> 16);
}

// ---- setup: LDS-tiled coalesced transpose to bf16 [j][k] + feats + counts
__global__ __launch_bounds__(512) void setup_kernel(
    const float* __restrict__ fc1w, const float* __restrict__ fc2w,
    ushort_t* __restrict__ fc1wT, ushort_t* __restrict__ fc2wT,
    const float* __restrict__ node, const float* __restrict__ l1,
    const float* __restrict__ plw, const float* __restrict__ plb,
    float* __restrict__ feats,
    const int* __restrict__ esrc, float* __restrict__ cnt)
{
  const int b = blockIdx.x, t = threadIdx.x;
  if (b < 28){
    __shared__ float sT[128*65];
    const int isfc1 = (b < 2);
    const float* src = isfc1 ? fc1w : fc2w;
    ushort_t* dst = isfc1 ? fc1wT : fc2wT;
    const int ncol = isfc1 ? 128 : 1664;
    const int j0 = isfc1 ? b*64 : (b-2)*64;
    const int lo = t & 63, hi = t >> 6;
    #pragma unroll
    for (int pass=0; pass<16; ++pass){
      const int k = pass*8 + hi;
      sT[k*65 + lo] = src[(size_t)k*ncol + j0 + lo];
    }
    __syncthreads();
    #pragma unroll
    for (int pass=0; pass<8; ++pass){
      const int j = pass*8 + hi;
      dst[(size_t)(j0+j)*128 + lo]      = f2bf(sT[lo*65 + j]);
      dst[(size_t)(j0+j)*128 + lo + 64] = f2bf(sT[(lo+64)*65 + j]);
    }
  } else if (b < 156){
    const int rr = (b-28)*8 + (t >> 6);
    const int u = t & 63;
    if (u < 32){
      float acc = plb[u];
      const float* nr = node + rr*256;
      #pragma unroll 4
      for (int c=0;c<256;c++) acc += nr[c]*plw[c*32+u];
      feats[rr*64+u] = acc;
    } else if (u < 56){
      feats[rr*64+u] = l1[rr*24 + (u-32)];
    }
  } else {
    const int ee = (b-156)*512 + t;
    atomicAdd(&cnt[esrc[ee]], 1.0f);
  }
}

// ================= fused MFMA edge kernel, register-resident apply =================
__global__ __launch_bounds__(NT, 2) void edge_kernel(
    const float* __restrict__ pair, const int* __restrict__ pidx,
    const int* __restrict__ esrc, const int* __restrict__ edst,
    const float* __restrict__ esh,
    const float* __restrict__ lng, const float* __restrict__ lnb,
    const ushort_t* __restrict__ fc1wT, const float* __restrict__ fc1b,
    const ushort_t* __restrict__ fc2wT, const float* __restrict__ fc2b,
    const float* __restrict__ feats, float* __restrict__ sums)
{
  __shared__ unsigned char Bbuf[2][32768];   // B tiles bf16 [128][256B] swizzled
  __shared__ unsigned char Hs[32768];        // h bf16, per-wave [16][256B] swizzled

  const int t = threadIdx.x;
  const int wv = t >> 6, l = t & 63;
  const int l15 = l & 15, lh = l >> 4;
  const int e0 = blockIdx.x * EB;
  const int ew = e0 + wv*16;
  const int p_ = l15 >> 3;

  const uint4* gW1 = (const uint4*)fc1wT;
  const uint4* gW2 = (const uint4*)fc2wT;
  uint4 pf[4];
  #pragma unroll
  for (int u=0;u<4;u++) pf[u] = gW1[u*NT + t];   // fc1wT in flight

  // ---- TP coefficients, 4-lane distributed register store (32 slots/lane)
  float cr[32];
  #pragma unroll
  for (int i=0;i<32;i++) cr[i]=0.f;
  {
    const int el = l >> 2, bank = l & 3;
    const int gc = e0 + wv*16 + el;
    const float* f = feats + (size_t)edst[gc]*64;
    const float* sh = esh + (size_t)gc*9;
    const float sh0 = sh[0];
    if (bank==0){                       // c1[u], slots 0..31
      #pragma unroll
      for (int u=0;u<32;u++) cr[u] = PW0c*sh0*f[u];
    } else if (bank==1){                // cx0[u], slots 32..63
      #pragma unroll
      for (int u=0;u<32;u++) cr[u] = PW1c*S3c*f[u];
    } else if (bank==2){                // c4 (64..71), b3 (72..95)
      const float s1x=sh[1], s1y=sh[2], s1z=sh[3];
      #pragma unroll
      for (int u=0;u<8;u++)
        cr[u] = PW0c*S3c*(f[32+3*u]*s1x + f[33+3*u]*s1y + f[34+3*u]*s1z);
      const float bc = PW1c*S3c*sh0;
      #pragma unroll
      for (int u=0;u<8;u++){
        cr[8+u*3+0] = bc*f[32+3*u+0];
        cr[8+u*3+1] = bc*f[32+3*u+1];
        cr[8+u*3+2] = bc*f[32+3*u+2];
      }
    } else {                            // t5p (96..119), sh1 (120..122)
      const float s20=sh[4],s21=sh[5],s22=sh[6],s23=sh[7],s24=sh[8];
      const float RXX = Kc*(-(1.f/3.f)*s22 - S3c*s24);
      const float RXY = Kc*S3c*s21;
      const float RXZ = Kc*S3c*s20;
      const float RYY = Kc*((2.f/3.f)*s22);
      const float RYZ = Kc*S3c*s23;
      const float RZZ = Kc*(-(1.f/3.f)*s22 + S3c*s24);
      #pragma unroll
      for (int u=0;u<8;u++){
        const float xx=f[32+3*u], xy=f[33+3*u], xz=f[34+3*u];
        cr[u*3+0] = PW1c*(xx*RXX + xy*RXY + xz*RXZ);
        cr[u*3+1] = PW1c*(xx*RXY + xy*RYY + xz*RYZ);
        cr[u*3+2] = PW1c*(xx*RXZ + xy*RYZ + xz*RZZ);
      }
      cr[24]=sh[1]; cr[25]=sh[2]; cr[26]=sh[3];
    }
  }
#define CF(Q,I) __shfl(cr[(I)&31], (l & 48) + (Q)*4 + ((I)>>5))

  // ---- LN of this lane's pair row -> A fragments in registers
  bf16x8 aF[4];
  {
    const int ge = ew + l15;
    const int pb = pidx[ge], pi_ = pidx[EDGES+ge], pj = pidx[2*EDGES+ge];
    const float4* prow = (const float4*)(pair + (((size_t)pb*LQ+pi_)*LQ+pj)*128);
    float4 v[8];
    #pragma unroll
    for (int kk=0;kk<4;kk++){
      v[kk*2]   = prow[kk*8 + lh*2];
      v[kk*2+1] = prow[kk*8 + lh*2 + 1];
    }
    float s=0.f, s2=0.f;
    #pragma unroll
    for (int k=0;k<8;k++){
      s  += v[k].x+v[k].y+v[k].z+v[k].w;
      s2 += v[k].x*v[k].x + v[k].y*v[k].y + v[k].z*v[k].z + v[k].w*v[k].w;
    }
    s  += __shfl_xor(s,16);  s  += __shfl_xor(s,32);
    s2 += __shfl_xor(s2,16); s2 += __shfl_xor(s2,32);
    const float mean = s * (1.f/128.f);
    const float var  = s2 * (1.f/128.f) - mean*mean;
    const float rstd = rsqrtf(var + 1e-5f);
    #pragma unroll
    for (int kk=0;kk<4;kk++){
      const int c0 = kk*32 + lh*8;
      const float4 g0 = *(const float4*)(lng + c0);
      const float4 g1 = *(const float4*)(lng + c0 + 4);
      const float4 b0 = *(const float4*)(lnb + c0);
      const float4 b1 = *(const float4*)(lnb + c0 + 4);
      union { bf16x8 v8; uint32 w[4]; } pk;
      pk.w[0] = (uint32)f2bf((v[kk*2].x-mean)*rstd*g0.x + b0.x)
              | ((uint32)f2bf((v[kk*2].y-mean)*rstd*g0.y + b0.y) << 16);
      pk.w[1] = (uint32)f2bf((v[kk*2].z-mean)*rstd*g0.z + b0.z)
              | ((uint32)f2bf((v[kk*2].w-mean)*rstd*g0.w + b0.w) << 16);
      pk.w[2] = (uint32)f2bf((v[kk*2+1].x-mean)*rstd*g1.x + b1.x)
              | ((uint32)f2bf((v[kk*2+1].y-mean)*rstd*g1.y + b1.y) << 16);
      pk.w[3] = (uint32)f2bf((v[kk*2+1].z-mean)*rstd*g1.z + b1.z)
              | ((uint32)f2bf((v[kk*2+1].w-mean)*rstd*g1.w + b1.w) << 16);
      aF[kk] = pk.v8;
    }
  }

  // stage fc1wT -> Bbuf[0]; issue chunk-0 loads
  #pragma unroll
  for (int u=0;u<4;u++){
    const int vi = u*NT + t; const int n = vi>>4; const int c = vi&15;
    *(uint4*)(Bbuf[0] + n*256 + ((c*16) ^ ((n&7)<<4))) = pf[u];
  }
  #pragma unroll
  for (int u=0;u<4;u++) pf[u] = gW2[u*NT + t];
  __syncthreads();   // Bbuf[0] ready

  // ---- fc1: h = relu(xn @ fc1w + b) -> wave-private Hs
  #pragma unroll
  for (int jt=0;jt<8;jt++){
    const float bj = fc1b[jt*16 + l15];
    f32x4 acc1 = {bj,bj,bj,bj};
    #pragma unroll
    for (int kk=0;kk<4;kk++){
      bf16x8 bf = *(const bf16x8*)(Bbuf[0] + (jt*16+l15)*256 + ((kk*64+lh*16) ^ ((l15&7)<<4)));
      acc1 = __builtin_amdgcn_mfma_f32_16x16x32_bf16(aF[kk], bf, acc1, 0,0,0);
    }
    #pragma unroll
    for (int q=0;q<4;q++){
      const int e = lh*4 + q;
      *(ushort_t*)(Hs + wv*4096 + e*256 + (((jt*16+l15)*2) ^ ((e&7)<<4)))
        = f2bf(fmaxf(acc1[q], 0.f));
    }
  }

  // stage chunk 0 -> Bbuf[1]; issue chunk-1 loads
  #pragma unroll
  for (int u=0;u<4;u++){
    const int vi = u*NT + t; const int n = vi>>4; const int c = vi&15;
    *(uint4*)(Bbuf[1] + n*256 + ((c*16) ^ ((n&7)<<4))) = pf[u];
  }
  #pragma unroll
  for (int u=0;u<4;u++) pf[u] = gW2[2048 + u*NT + t];
  __syncthreads();   // Bbuf[1] ready, h visible

  // h A-fragments (constant across all 13 chunks)
  bf16x8 a2[4];
  #pragma unroll
  for (int kk=0;kk<4;kk++)
    a2[kk] = *(const bf16x8*)(Hs + wv*4096 + l15*256 + ((kk*64+lh*16) ^ ((l15&7)<<4)));

  float o0[4][2] = {{0.f,0.f},{0.f,0.f},{0.f,0.f},{0.f,0.f}};
  float o1[4][3] = {{0.f,0.f,0.f},{0.f,0.f,0.f},{0.f,0.f,0.f},{0.f,0.f,0.f}};

#define APPLY(CB) do{                                                          \
  if ((CB) < 8){                                                               \
    _Pragma("unroll")                                                          \
    for (int q=0;q<4;q++){                                                     \
      _Pragma("unroll")                                                        \
      for (int jt=0;jt<8;jt++)                                                 \
        o0[q][jt&1] += CF(q, (CB)*4 + (jt>>1)) * acc[jt][q];                   \
    }                                                                          \
  } else if ((CB) < 10){                                                       \
    _Pragma("unroll")                                                          \
    for (int q=0;q<4;q++){                                                     \
      float S = 0.f;                                                           \
      _Pragma("unroll")                                                        \
      for (int jt=0;jt<8;jt++){                                                \
        const float ce = CF(q, 32 + ((CB)-8)*16 + jt*2);                       \
        const float co = CF(q, 33 + ((CB)-8)*16 + jt*2);                       \
        S += (p_ ? co : ce) * acc[jt][q];                                      \
      }                                                                        \
      o1[q][0] += S*CF(q,120); o1[q][1] += S*CF(q,121); o1[q][2] += S*CF(q,122);\
    }                                                                          \
  } else if ((CB)==10){                                                        \
    _Pragma("unroll")                                                          \
    for (int q=0;q<4;q++){                                                     \
      _Pragma("unroll")                                                        \
      for (int m=0;m<3;m++){                                                   \
        float S=0.f;                                                           \
        _Pragma("unroll")                                                      \
        for (int jt=0;jt<4;jt++){                                              \
          const float ce = CF(q, 72 + jt*6 + m);                               \
          const float co = CF(q, 75 + jt*6 + m);                               \
          S += (p_ ? co : ce) * acc[jt][q];                                    \
        }                                                                      \
        o1[q][m] += S;                                                         \
      }                                                                        \
      _Pragma("unroll")                                                        \
      for (int jt=4;jt<8;jt++)                                                 \
        o0[q][jt&1] += CF(q, 64 + ((jt-4)>>1)) * acc[jt][q];                   \
    }                                                                          \
  } else if ((CB)==11){                                                        \
    _Pragma("unroll")                                                          \
    for (int q=0;q<4;q++)                                                      \
      for (int jt=0;jt<8;jt++)                                                 \
        o0[q][jt&1] += CF(q, 66 + (jt>>1)) * acc[jt][q];                       \
  } else {                                                                     \
    _Pragma("unroll")                                                          \
    for (int q=0;q<4;q++){                                                     \
      _Pragma("unroll")                                                        \
      for (int jt=0;jt<4;jt++)                                                 \
        o0[q][jt&1] += CF(q, 70 + (jt>>1)) * acc[jt][q];                       \
      _Pragma("unroll")                                                        \
      for (int m=0;m<3;m++){                                                   \
        float S=0.f;                                                           \
        _Pragma("unroll")                                                      \
        for (int jt=4;jt<8;jt++){                                              \
          const float ce = CF(q, 96 + (jt-4)*6 + m);                           \
          const float co = CF(q, 99 + (jt-4)*6 + m);                           \
          S += (p_ ? co : ce) * acc[jt][q];                                    \
        }                                                                      \
        o1[q][m] += S;                                                         \
      }                                                                        \
    }                                                                          \
  }                                                                            \
} while(0)

#define CHUNK(CB) do{                                                          \
    const unsigned char* Bc = Bbuf[((CB)&1)^1];                                \
    f32x4 acc[8];                                                              \
    _Pragma("unroll")                                                          \
    for (int jt=0;jt<8;jt++){                                                  \
      const float bj = fc2b[(CB)*128 + jt*16 + l15];                           \
      acc[jt][0]=bj; acc[jt][1]=bj; acc[jt][2]=bj; acc[jt][3]=bj;              \
      _Pragma("unroll")                                                        \
      for (int kk=0;kk<4;kk++){                                                \
        bf16x8 bf = *(const bf16x8*)(Bc + (jt*16+l15)*256 + ((kk*64+lh*16) ^ ((l15&7)<<4))); \
        acc[jt] = __builtin_amdgcn_mfma_f32_16x16x32_bf16(a2[kk], bf, acc[jt], 0,0,0); \
      }                                                                        \
    }                                                                          \
    if ((CB) <= 11){                                                           \
      unsigned char* Bn = (unsigned char*)Bbuf[(CB)&1];                        \
      _Pragma("unroll")                                                        \
      for (int u=0;u<4;u++){                                                   \
        const int vi = u*NT + t; const int n = vi>>4; const int c = vi&15;     \
        *(uint4*)(Bn + n*256 + ((c*16) ^ ((n&7)<<4))) = pf[u];                 \
      }                                                                        \
      if ((CB) <= 10){                                                         \
        _Pragma("unroll")                                                      \
        for (int u=0;u<4;u++) pf[u] = gW2[((CB)+2)*2048 + u*NT + t];           \
      }                                                                        \
    }                                                                          \
    APPLY(CB);                                                                 \
    __syncthreads();                                                           \
  } while(0)

  CHUNK(0);  CHUNK(1);  CHUNK(2);  CHUNK(3);
  CHUNK(4);  CHUNK(5);  CHUNK(6);  CHUNK(7);
  CHUNK(8);  CHUNK(9);  CHUNK(10); CHUNK(11);
  CHUNK(12);

  // ---- segment atomic add
  #pragma unroll
  for (int q=0;q<4;q++){
    const int src = esrc[ew + lh*4 + q];
    float* srow = sums + (size_t)src*64;
    atomicAdd(srow + l15,      o0[q][0]);
    atomicAdd(srow + 16 + l15, o0[q][1]);
    #pragma unroll
    for (int m=0;m<3;m++){
      float vv = o1[q][m] + __shfl_xor(o1[q][m], 8);
      if (l15 < 8) atomicAdd(srow + 32 + l15*3 + m, vv);
    }
  }
}

// ---- finalize: mean, node projection + residuals, write outputs
__global__ __launch_bounds__(256) void finalize_kernel(
    const float* __restrict__ sums, const float* __restrict__ cnt,
    const float* __restrict__ node, const float* __restrict__ l1,
    const float* __restrict__ pw, const float* __restrict__ pb,
    float* __restrict__ out)
{
  __shared__ float so[56];
  const int rnode = blockIdx.x;
  const int t = threadIdx.x;
  if (t < 56){
    const float c = cnt[rnode];
    so[t] = sums[rnode*64+t] / fmaxf(c, 1.0f);
  }
  __syncthreads();
  float acc = pb[t] + node[rnode*256+t];
  #pragma unroll
  for (int k=0;k<32;k++) acc += so[k]*pw[k*256+t];
  out[rnode*256+t] = acc;
  if (t < 24) out[NNODE*256 + rnode*24 + t] = so[32+t] + l1[rnode*24+t];
}

extern "C" void kernel_launch(void* const* d_in, const int* in_sizes, int n_in,
                              void* d_out, int out_size, void* d_ws, size_t ws_size,
                              hipStream_t stream)
{
  const float* node = (const float*)d_in[0];
  const float* pair = (const float*)d_in[1];
  const float* l1f  = (const float*)d_in[2];
  const float* esh  = (const float*)d_in[3];
  const float* plw  = (const float*)d_in[4];
  const float* plb  = (const float*)d_in[5];
  const float* pnw  = (const float*)d_in[6];
  const float* pnb  = (const float*)d_in[7];
  const float* lng  = (const float*)d_in[8];
  const float* lnb  = (const float*)d_in[9];
  const float* fc1w = (const float*)d_in[10];
  const float* fc1b = (const float*)d_in[11];
  const float* fc2w = (const float*)d_in[12];
  const float* fc2b = (const float*)d_in[13];
  const int* pidx = (const int*)d_in[14];
  const int* esrc = (const int*)d_in[15];
  const int* edst = (const int*)d_in[16];
  float* out = (float*)d_out;
  float* ws = (float*)d_ws;
  float* feats = ws;                            // 65536 f32
  float* sums  = ws + 65536;                    // 65536 f32
  float* cnt   = ws + 131072;                   // 1024 f32
  ushort_t* fc1wT = (ushort_t*)(ws + 132096);   // 16384 bf16
  ushort_t* fc2wT = fc1wT + 16384;              // 212992 bf16

  hipMemsetAsync(sums, 0, (65536+1024)*sizeof(float), stream);
  setup_kernel<<<dim3(284), dim3(512), 0, stream>>>(fc1w, fc2w, fc1wT, fc2wT,
      node, l1f, plw, plb, feats, esrc, cnt);
  edge_kernel<<<dim3(512), dim3(NT), 0, stream>>>(pair, pidx, esrc, edst, esh,
      lng, lnb, fc1wT, fc1b, fc2wT, fc2b, feats, sums);
  finalize_kernel<<<dim3(1024), dim3(256), 0, stream>>>(sums, cnt, node, l1f, pnw, pnb, out);
}